// Round 5
// baseline (450.821 us; speedup 1.0000x reference)
//
#include <hip/hip_runtime.h>
#include <hip/hip_bf16.h>

// InteractionBlock: B=16,N=192,H=128,F=128,G=50.
// DTYPE: all tensor inputs and the output are FP32 (R2/R3/R4 bisect: hard-coded
// bf16 reads fail deterministically with identical absmax under three different
// staging/reduction variants; R1 passed only via its runtime detector choosing
// fp32. R1's "bf16 proven by FETCH_SIZE=65MB" was the L3-absorption gotcha —
// fp32 rbf (118MB) fits in the 256MB Infinity Cache.)
//
// 2 launches:
//  pre_kernel  : nf = features@Wf+bf (f32 ws) + W1/W2 transpose -> bf16 [n][k]
//  main_kernel : per (b,i): stage rbf row-block fp32->bf16 into LDS (float4
//                loads, packed 8B LDS stores), GEMM1(mfma bf16)->softplus->s_hs,
//                GEMM2(mfma), masked nf-weighted reduction (LDS atomicAdd,
//                R1-proven), fused out-MLP tail, fp32 store.

typedef __bf16 bf16_t;
typedef __bf16 bf16x8 __attribute__((ext_vector_type(8)));
typedef float  f32x4  __attribute__((ext_vector_type(4)));

constexpr int kN = 192, kH = 128, kF = 128, kG = 50;
constexpr int kRows = 16 * kN;            // 3072
constexpr int kHsPitch = 136;             // bf16 elems; rows 272 B, 16B-aligned
constexpr int kRbfRowB = kG * 2;          // staged (bf16) row = 100 B
constexpr int kRbfF32PerBlk = kN * kG;    // 9600 floats per (b,i)
constexpr int kRbfVec4 = kRbfF32PerBlk / 4;  // 2400 float4 chunks

__device__ __forceinline__ float softplus_f(float x) {
  float t = __logf(1.f + __expf(fminf(x, 20.f)));
  return x > 20.f ? x : t;
}

// ---- prologue: nf rows + (blocks kRows..kRows+1) weight transposes ----
__global__ __launch_bounds__(64) void pre_kernel(
    const float* __restrict__ features, const float* __restrict__ Wf,
    const float* __restrict__ bfv, const float* __restrict__ W1,
    const float* __restrict__ W2, float* __restrict__ nf,
    bf16_t* __restrict__ w1t, bf16_t* __restrict__ w2t) {
  const int lane = threadIdx.x;
  if (blockIdx.x >= kRows) {
    if (blockIdx.x == kRows) {          // w1t[n][k] 128x64, zero-pad k>=50
      for (int i = lane; i < 128 * 64; i += 64) {
        int n = i >> 6, k = i & 63;
        w1t[i] = (k < kG) ? (bf16_t)W1[k * kF + n] : (bf16_t)0.f;
      }
    } else {                            // w2t[n][k] 128x128
      for (int i = lane; i < 128 * 128; i += 64) {
        int n = i >> 7, k = i & 127;
        w2t[i] = (bf16_t)W2[k * kF + n];
      }
    }
    return;
  }
  const int row = blockIdx.x;
  __shared__ float s_x[kH];
  const float* fr = features + (size_t)row * kH;
  s_x[lane] = fr[lane];
  s_x[64 + lane] = fr[64 + lane];
  __syncthreads();
  float a0 = bfv[lane], a1 = bfv[64 + lane];
#pragma unroll 8
  for (int k = 0; k < kH; ++k) {
    float xk = s_x[k];
    a0 = fmaf(xk, Wf[k * kF + lane], a0);
    a1 = fmaf(xk, Wf[k * kF + 64 + lane], a1);
  }
  float* nr = nf + (size_t)row * kF;
  nr[lane] = a0;
  nr[64 + lane] = a1;
}

// ---- main ----
__global__ __launch_bounds__(256) void main_kernel(
    const float* __restrict__ rbf, const int* __restrict__ nmask,
    const float* __restrict__ b1p, const float* __restrict__ b2p,
    const bf16_t* __restrict__ w1t, const bf16_t* __restrict__ w2t,
    const float* __restrict__ nf, const float* __restrict__ features,
    const float* __restrict__ Wo1, const float* __restrict__ bo1,
    const float* __restrict__ Wo2, const float* __restrict__ bo2,
    float* __restrict__ out) {
  // LDS 54016 B -> 3 blocks/CU. [0,52224): s_hs (192x136 bf16); staged bf16
  // rbf occupies [0,19200) before GEMM1 (barrier-separated alias).
  __shared__ __align__(16) char smem[54016];
  bf16_t* s_hs   = (bf16_t*)smem;
  float*  s_mask = (float*)(smem + 52224);   // 192 f32
  float*  s_agg  = (float*)(smem + 52992);   // 128 f32
  float*  s_tt   = (float*)(smem + 53504);   // 128 f32

  const int bi = blockIdx.x;
  const int b  = bi / kN;
  const int t  = threadIdx.x;
  const int wave = t >> 6, lane = t & 63;
  const int n16 = lane & 15, q = lane >> 4;
  const int m0w = wave * 48;

  // stage rbf[bi]: fp32 global -> bf16 LDS (19200 B region)
  {
    const float4* g4 = (const float4*)(rbf + (size_t)bi * kRbfF32PerBlk);
#pragma unroll
    for (int it = 0; it < 10; ++it) {
      int c = it * 256 + t;
      if (c < kRbfVec4) {
        float4 v = g4[c];
        union { bf16_t h[4]; uint2 u2; } pk;
        pk.h[0] = (bf16_t)v.x; pk.h[1] = (bf16_t)v.y;
        pk.h[2] = (bf16_t)v.z; pk.h[3] = (bf16_t)v.w;
        *(uint2*)(smem + c * 8) = pk.u2;
      }
    }
  }
  if (t < kN) s_mask[t] = (float)nmask[(size_t)bi * kN + t];
  if (t < kF) s_agg[t] = 0.f;
  __syncthreads();

  f32x4 acc[3][8];
#pragma unroll
  for (int mt = 0; mt < 3; ++mt)
#pragma unroll
    for (int nt = 0; nt < 8; ++nt)
#pragma unroll
      for (int r = 0; r < 4; ++r) acc[mt][nt][r] = 0.f;

  // GEMM1: [192, 50->64] @ w1t. A from LDS: row j at byte j*100 (div by 4);
  // lane k-base ks*32+q*8 -> dwords dwb=ks*16+q*4 .. +3; k>=50 <=> dword>=25.
#pragma unroll
  for (int ks = 0; ks < 2; ++ks) {
    bf16x8 afr[3];
#pragma unroll
    for (int mt = 0; mt < 3; ++mt) {
      const int j = m0w + mt * 16 + n16;
      const unsigned* rowp = (const unsigned*)(smem + j * kRbfRowB);
      const int dwb = ks * 16 + q * 4;
      union { unsigned u[4]; bf16x8 v; } cc;
#pragma unroll
      for (int c = 0; c < 4; ++c) {
        unsigned val = rowp[dwb + c];           // max byte 19227 < 52224
        cc.u[c] = (dwb + c <= 24) ? val : 0u;
      }
      afr[mt] = cc.v;
    }
#pragma unroll
    for (int nt = 0; nt < 8; ++nt) {
      bf16x8 bfr = *(const bf16x8*)(w1t + (nt * 16 + n16) * 64 + ks * 32 + q * 8);
#pragma unroll
      for (int mt = 0; mt < 3; ++mt)
        acc[mt][nt] = __builtin_amdgcn_mfma_f32_16x16x32_bf16(afr[mt], bfr, acc[mt][nt], 0, 0, 0);
    }
  }
  __syncthreads();   // staged-rbf reads complete before s_hs overwrite

  // bias + softplus -> s_hs bf16. C/D layout: col=lane&15, row=q*4+r.
#pragma unroll
  for (int nt = 0; nt < 8; ++nt) {
    const int col = nt * 16 + n16;
    const float bb = b1p[col];
#pragma unroll
    for (int mt = 0; mt < 3; ++mt) {
      const int jb = m0w + mt * 16 + q * 4;
#pragma unroll
      for (int r = 0; r < 4; ++r)
        s_hs[(jb + r) * kHsPitch + col] = (bf16_t)softplus_f(acc[mt][nt][r] + bb);
    }
  }
  __syncthreads();

  // GEMM2: [192,128] @ w2t
#pragma unroll
  for (int mt = 0; mt < 3; ++mt)
#pragma unroll
    for (int nt = 0; nt < 8; ++nt)
#pragma unroll
      for (int r = 0; r < 4; ++r) acc[mt][nt][r] = 0.f;

#pragma unroll
  for (int ks = 0; ks < 4; ++ks) {
    bf16x8 afr[3];
#pragma unroll
    for (int mt = 0; mt < 3; ++mt)
      afr[mt] = *(const bf16x8*)(s_hs + (m0w + mt * 16 + n16) * kHsPitch + ks * 32 + q * 8);
#pragma unroll
    for (int nt = 0; nt < 8; ++nt) {
      bf16x8 bfr = *(const bf16x8*)(w2t + (nt * 16 + n16) * 128 + ks * 32 + q * 8);
#pragma unroll
      for (int mt = 0; mt < 3; ++mt)
        acc[mt][nt] = __builtin_amdgcn_mfma_f32_16x16x32_bf16(afr[mt], bfr, acc[mt][nt], 0, 0, 0);
    }
  }

  // epilogue: p = sum over lane's 12 rows of mask*(fw+b2)*nf -> s_agg (atomic)
  const float* nfb = nf + (size_t)b * kN * kF;
#pragma unroll
  for (int nt = 0; nt < 8; ++nt) {
    const int f = nt * 16 + n16;
    const float b2v = b2p[f];
    float p = 0.f;
#pragma unroll
    for (int mt = 0; mt < 3; ++mt) {
      const int jb = m0w + mt * 16 + q * 4;
#pragma unroll
      for (int r = 0; r < 4; ++r) {
        const int j = jb + r;
        p = fmaf(s_mask[j] * (acc[mt][nt][r] + b2v), nfb[(size_t)j * kF + f], p);
      }
    }
    atomicAdd(&s_agg[f], p);
  }
  __syncthreads();

  // fused out-MLP: out = features + softplus(agg@Wo1+bo1)@Wo2+bo2
  if (t < kH) {
    float a1 = bo1[t];
#pragma unroll 8
    for (int k = 0; k < kF; ++k) a1 = fmaf(s_agg[k], Wo1[k * kH + t], a1);
    s_tt[t] = softplus_f(a1);
  }
  __syncthreads();
  if (t < kH) {
    float a2 = bo2[t];
#pragma unroll 8
    for (int k = 0; k < kH; ++k) a2 = fmaf(s_tt[k], Wo2[k * kH + t], a2);
    out[(size_t)bi * kH + t] = features[(size_t)bi * kH + t] + a2;
  }
}

extern "C" void kernel_launch(void* const* d_in, const int* in_sizes, int n_in,
                              void* d_out, int out_size, void* d_ws, size_t ws_size,
                              hipStream_t stream) {
  const float* features = (const float*)d_in[0];
  const float* rbf      = (const float*)d_in[1];
  const int*   nmask    = (const int*)d_in[2];
  const float* W1  = (const float*)d_in[3];
  const float* b1  = (const float*)d_in[4];
  const float* W2  = (const float*)d_in[5];
  const float* b2  = (const float*)d_in[6];
  const float* Wf  = (const float*)d_in[7];
  const float* bfv = (const float*)d_in[8];
  const float* Wo1 = (const float*)d_in[9];
  const float* bo1 = (const float*)d_in[10];
  const float* Wo2 = (const float*)d_in[11];
  const float* bo2 = (const float*)d_in[12];

  char* ws = (char*)d_ws;
  float*  nf  = (float*)ws;                    // 3072*128 f32 = 1,572,864 B
  bf16_t* w1t = (bf16_t*)(ws + 1572864);       // 128*64  bf16 = 16,384 B
  bf16_t* w2t = (bf16_t*)(ws + 1589248);       // 128*128 bf16 = 32,768 B

  pre_kernel<<<kRows + 2, 64, 0, stream>>>(features, Wf, bfv, W1, W2, nf, w1t, w2t);
  main_kernel<<<kRows, 256, 0, stream>>>(rbf, nmask, b1, b2, w1t, w2t, nf,
                                         features, Wo1, bo1, Wo2, bo2, (float*)d_out);
}

// Round 6
// 447.163 us; speedup vs baseline: 1.0082x; 1.0082x over previous
//
#include <hip/hip_runtime.h>
#include <hip/hip_bf16.h>

// InteractionBlock: B=16,N=192,H=128,F=128,G=50. ALL tensors fp32 (R5-proven).
//
// R5 lesson (counters): VALU-busy identical R1 vs R5 (63 us); regression was
// pure stall from GEMV-shaped serial loops at low occupancy. R6 structure:
//  pre_kernel  : per-row k-split GEMV nf = features@Wf+bf  (3072 blocks)
//                + W1/W2 transposes + zero agg              (+386 blocks)
//  main_kernel : one block per (b,i,jhalf): 6144 x 128 thr, LDS 27 KB ->
//                6 blocks/CU. Stage rbf half (fp32->bf16 LDS), GEMM1 (mfma)
//                -> softplus -> s_hs, GEMM2 (mfma), masked nf-weighted reduce
//                -> global atomicAdd into agg (2-way contention).
//  post_kernel : per-row k-split GEMV out = features + softplus(agg@Wo1+bo1)@Wo2+bo2

typedef __bf16 bf16_t;
typedef __bf16 bf16x8 __attribute__((ext_vector_type(8)));
typedef float  f32x4  __attribute__((ext_vector_type(4)));

constexpr int kN = 192, kH = 128, kF = 128, kG = 50;
constexpr int kRows = 16 * kN;            // 3072
constexpr int kHsPitch = 136;             // bf16 elems; rows 272 B
constexpr int kJH = 96;                   // j-rows per main block (half of N)
constexpr int kRbfRowB = kG * 2;          // staged bf16 row = 100 B
constexpr int kStageF32 = kJH * kG;       // 4800 floats per block
constexpr int kStageV4 = kStageF32 / 4;   // 1200 float4
constexpr int kAggV4 = kRows * kF / 4;    // 98304 float4 to zero

__device__ __forceinline__ float softplus_f(float x) {
  float t = __logf(1.f + __expf(fminf(x, 20.f)));
  return x > 20.f ? x : t;
}

// ---- pre: blocks [0,3072) nf rows; 3072/3073 transposes; 3074.. zero agg ----
__global__ __launch_bounds__(256) void pre_kernel(
    const float* __restrict__ features, const float* __restrict__ Wf,
    const float* __restrict__ bfv, const float* __restrict__ W1,
    const float* __restrict__ W2, float* __restrict__ nf,
    bf16_t* __restrict__ w1t, bf16_t* __restrict__ w2t,
    float* __restrict__ agg) {
  const int t = threadIdx.x;
  const int blk = blockIdx.x;
  if (blk >= kRows) {
    if (blk == kRows) {                    // w1t[n][k] 128x64, pad k>=50
      for (int i = t; i < 128 * 64; i += 256) {
        int n = i >> 6, k = i & 63;
        w1t[i] = (k < kG) ? (bf16_t)W1[k * kF + n] : (bf16_t)0.f;
      }
    } else if (blk == kRows + 1) {         // w2t[n][k] 128x128
      for (int i = t; i < 128 * 128; i += 256) {
        int n = i >> 7, k = i & 127;
        w2t[i] = (bf16_t)W2[k * kF + n];
      }
    } else {                               // zero agg
      int idx = (blk - (kRows + 2)) * 256 + t;
      if (idx < kAggV4) ((float4*)agg)[idx] = make_float4(0.f, 0.f, 0.f, 0.f);
    }
    return;
  }
  // nf[row] = features[row] @ Wf + bf, k split in halves across t>>7
  __shared__ float s_x[kH];
  __shared__ float s_red[256];
  const int h2 = t & 127, half = t >> 7;
  if (t < kH) s_x[t] = features[(size_t)blk * kH + t];
  __syncthreads();
  float acc = half ? 0.f : bfv[h2];
  const int k0 = half * 64;
#pragma unroll 8
  for (int k = k0; k < k0 + 64; ++k) acc = fmaf(s_x[k], Wf[k * kF + h2], acc);
  s_red[t] = acc;
  __syncthreads();
  if (t < kF) nf[(size_t)blk * kF + t] = s_red[t] + s_red[t + 128];
}

// ---- main: block = (b,i,jhalf) ----
__global__ __launch_bounds__(128) void main_kernel(
    const float* __restrict__ rbf, const int* __restrict__ nmask,
    const float* __restrict__ b1p, const float* __restrict__ b2p,
    const bf16_t* __restrict__ w1t, const bf16_t* __restrict__ w2t,
    const float* __restrict__ nf, float* __restrict__ agg) {
  // LDS 27008 B -> 6 blocks/CU. [0,26112): s_hs (96x136 bf16); staged bf16
  // rbf occupies [0,9600) before GEMM1 (barrier-separated alias).
  __shared__ __align__(16) char smem[27008];
  bf16_t* s_hs   = (bf16_t*)smem;
  float*  s_mask = (float*)(smem + 26112);   // 96 f32
  float*  s_agg  = (float*)(smem + 26496);   // 128 f32

  const int bih = blockIdx.x;
  const int jh  = bih & 1;                   // j-half
  const int bi  = bih >> 1;                  // (b*192 + i)
  const int b   = bi / kN;
  const int t   = threadIdx.x;
  const int wave = t >> 6, lane = t & 63;    // wave in {0,1}
  const int n16 = lane & 15, q = lane >> 4;
  const int m0w = wave * 48;                 // rows [m0w, m0w+48) of this half

  // stage rbf[bi, jh*96 .. +96) : fp32 -> bf16 LDS (9600 B region)
  {
    const float4* g4 = (const float4*)(rbf + (size_t)bi * (kN * kG) + jh * kStageF32);
#pragma unroll
    for (int it = 0; it < 10; ++it) {
      int c = it * 128 + t;
      if (c < kStageV4) {
        float4 v = g4[c];
        union { bf16_t h[4]; uint2 u2; } pk;
        pk.h[0] = (bf16_t)v.x; pk.h[1] = (bf16_t)v.y;
        pk.h[2] = (bf16_t)v.z; pk.h[3] = (bf16_t)v.w;
        *(uint2*)(smem + c * 8) = pk.u2;
      }
    }
  }
  if (t < kJH) s_mask[t] = (float)nmask[(size_t)bi * kN + jh * kJH + t];
  if (t < kF) s_agg[t] = 0.f;
  __syncthreads();

  f32x4 acc[3][8];
#pragma unroll
  for (int mt = 0; mt < 3; ++mt)
#pragma unroll
    for (int nt = 0; nt < 8; ++nt)
#pragma unroll
      for (int r = 0; r < 4; ++r) acc[mt][nt][r] = 0.f;

  // GEMM1: [96, 50->64] @ w1t. A row j at byte j*100; dwords dwb..dwb+3;
  // k>=50 <=> dword>=25 (dword 24 = k48,49 is the last valid).
#pragma unroll
  for (int ks = 0; ks < 2; ++ks) {
    bf16x8 afr[3];
#pragma unroll
    for (int mt = 0; mt < 3; ++mt) {
      const int j = m0w + mt * 16 + n16;
      const unsigned* rowp = (const unsigned*)(smem + j * kRbfRowB);
      const int dwb = ks * 16 + q * 4;
      union { unsigned u[4]; bf16x8 v; } cc;
#pragma unroll
      for (int c = 0; c < 4; ++c) {
        unsigned val = rowp[dwb + c];            // max byte 9608 < 26112
        cc.u[c] = (dwb + c <= 24) ? val : 0u;
      }
      afr[mt] = cc.v;
    }
#pragma unroll
    for (int nt = 0; nt < 8; ++nt) {
      bf16x8 bfr = *(const bf16x8*)(w1t + (nt * 16 + n16) * 64 + ks * 32 + q * 8);
#pragma unroll
      for (int mt = 0; mt < 3; ++mt)
        acc[mt][nt] = __builtin_amdgcn_mfma_f32_16x16x32_bf16(afr[mt], bfr, acc[mt][nt], 0, 0, 0);
    }
  }
  __syncthreads();   // staged-rbf reads complete before s_hs overwrite

  // bias + softplus -> s_hs bf16. C/D: col=lane&15, row=q*4+r.
#pragma unroll
  for (int nt = 0; nt < 8; ++nt) {
    const int col = nt * 16 + n16;
    const float bb = b1p[col];
#pragma unroll
    for (int mt = 0; mt < 3; ++mt) {
      const int jb = m0w + mt * 16 + q * 4;
#pragma unroll
      for (int r = 0; r < 4; ++r)
        s_hs[(jb + r) * kHsPitch + col] = (bf16_t)softplus_f(acc[mt][nt][r] + bb);
    }
  }
  __syncthreads();

  // GEMM2: [96,128] @ w2t
#pragma unroll
  for (int mt = 0; mt < 3; ++mt)
#pragma unroll
    for (int nt = 0; nt < 8; ++nt)
#pragma unroll
      for (int r = 0; r < 4; ++r) acc[mt][nt][r] = 0.f;

#pragma unroll
  for (int ks = 0; ks < 4; ++ks) {
    bf16x8 afr[3];
#pragma unroll
    for (int mt = 0; mt < 3; ++mt)
      afr[mt] = *(const bf16x8*)(s_hs + (m0w + mt * 16 + n16) * kHsPitch + ks * 32 + q * 8);
#pragma unroll
    for (int nt = 0; nt < 8; ++nt) {
      bf16x8 bfr = *(const bf16x8*)(w2t + (nt * 16 + n16) * 128 + ks * 32 + q * 8);
#pragma unroll
      for (int mt = 0; mt < 3; ++mt)
        acc[mt][nt] = __builtin_amdgcn_mfma_f32_16x16x32_bf16(afr[mt], bfr, acc[mt][nt], 0, 0, 0);
    }
  }

  // epilogue: p = sum over lane's 12 local rows of mask*(fw+b2)*nf -> s_agg
  const float* nfb = nf + (size_t)b * kN * kF;
#pragma unroll
  for (int nt = 0; nt < 8; ++nt) {
    const int f = nt * 16 + n16;
    const float b2v = b2p[f];
    float p = 0.f;
#pragma unroll
    for (int mt = 0; mt < 3; ++mt) {
      const int jb = m0w + mt * 16 + q * 4;
#pragma unroll
      for (int r = 0; r < 4; ++r) {
        const int jl = jb + r;                       // local row in [0,96)
        const int jg = jh * kJH + jl;                // global j
        p = fmaf(s_mask[jl] * (acc[mt][nt][r] + b2v), nfb[(size_t)jg * kF + f], p);
      }
    }
    atomicAdd(&s_agg[f], p);
  }
  __syncthreads();
  if (t < kF) atomicAdd(&agg[(size_t)bi * kF + t], s_agg[t]);
}

// ---- post: per-row k-split GEMV out = features + softplus(agg@Wo1+bo1)@Wo2+bo2 ----
__global__ __launch_bounds__(256) void post_kernel(
    const float* __restrict__ agg, const float* __restrict__ features,
    const float* __restrict__ Wo1, const float* __restrict__ bo1,
    const float* __restrict__ Wo2, const float* __restrict__ bo2,
    float* __restrict__ out) {
  __shared__ float s_a[kF];
  __shared__ float s_red[256];
  __shared__ float s_t[kH];
  const int row = blockIdx.x, t = threadIdx.x;
  const int h2 = t & 127, half = t >> 7;
  const int k0 = half * 64;
  if (t < kF) s_a[t] = agg[(size_t)row * kF + t];
  __syncthreads();
  float a1 = half ? 0.f : bo1[h2];
#pragma unroll 8
  for (int k = k0; k < k0 + 64; ++k) a1 = fmaf(s_a[k], Wo1[k * kH + h2], a1);
  s_red[t] = a1;
  __syncthreads();
  if (t < kH) s_t[t] = softplus_f(s_red[t] + s_red[t + 128]);
  __syncthreads();
  float a2 = half ? 0.f : bo2[h2];
#pragma unroll 8
  for (int k = k0; k < k0 + 64; ++k) a2 = fmaf(s_t[k], Wo2[k * kH + h2], a2);
  s_red[t] = a2;
  __syncthreads();
  if (t < kH)
    out[(size_t)row * kH + t] = features[(size_t)row * kH + t] + s_red[t] + s_red[t + 128];
}

extern "C" void kernel_launch(void* const* d_in, const int* in_sizes, int n_in,
                              void* d_out, int out_size, void* d_ws, size_t ws_size,
                              hipStream_t stream) {
  const float* features = (const float*)d_in[0];
  const float* rbf      = (const float*)d_in[1];
  const int*   nmask    = (const int*)d_in[2];
  const float* W1  = (const float*)d_in[3];
  const float* b1  = (const float*)d_in[4];
  const float* W2  = (const float*)d_in[5];
  const float* b2  = (const float*)d_in[6];
  const float* Wf  = (const float*)d_in[7];
  const float* bfv = (const float*)d_in[8];
  const float* Wo1 = (const float*)d_in[9];
  const float* bo1 = (const float*)d_in[10];
  const float* Wo2 = (const float*)d_in[11];
  const float* bo2 = (const float*)d_in[12];

  char* ws = (char*)d_ws;
  float*  nf  = (float*)ws;                    // 3072*128 f32 = 1,572,864 B
  float*  agg = (float*)(ws + 1572864);        // 1,572,864 B
  bf16_t* w1t = (bf16_t*)(ws + 3145728);       // 16,384 B
  bf16_t* w2t = (bf16_t*)(ws + 3162112);       // 32,768 B  (total 3,194,880)

  const int nZero = (kAggV4 + 255) / 256;      // 384
  pre_kernel<<<kRows + 2 + nZero, 256, 0, stream>>>(features, Wf, bfv, W1, W2,
                                                    nf, w1t, w2t, agg);
  main_kernel<<<kRows * 2, 128, 0, stream>>>(rbf, nmask, b1, b2, w1t, w2t, nf, agg);
  post_kernel<<<kRows, 256, 0, stream>>>(agg, features, Wo1, bo1, Wo2, bo2, (float*)d_out);
}